// Round 9
// baseline (280.382 us; speedup 1.0000x reference)
//
#include <hip/hip_runtime.h>

// DISCO S2 conv, equiangular 360x720 -> 180x360, K=3, B*C=128.
// out[bc, k*180+t, p] = sum_{e in seg(k,t)} val[e]*qw[lat[e]] * x[bc, lat[e], (lon[e]-2p-2) mod 720]
//
// Round-9: p-register-blocking (PB=3) on w-contiguous runs.
//  - Entries of a row form runs of consecutive w (dual parity). Thread owns
//    p0..p0+2; keeps a 3-deep float4 (4ch) register window per parity plane;
//    per entry: 1 ds_read_b128 + 12 FMA -> 1.33 B/MAC (3x less LDS traffic).
//  - lane slot stride = 3 (odd) -> conflict-free reads, no swizzle.
//  - 256 thr = 2 p-pairs x 2 waves; rows assigned to pair by (j&1) (matches
//    plane pairs); pair-1 accumulators combined via LDS at the end.
//  - pole constant-val full rows collapse to wave-local rowsum (no barriers).
//  - runs prebuilt in ws (e0, w0, len<=64); cf in original entry order.

#define NLAT_IN  360
#define NLON_IN  720
#define NLAT_OUT 180
#define NLON_OUT 360
#define KSIZE    3
#define NSEG     (KSIZE * NLAT_OUT)    // 540
#define CHW      (NLAT_IN * NLON_IN)   // 259200
#define BCTOT    128
#define G        4
#define NBCG     (BCTOT / G)           // 32
#define MAXR     2
#define PH       10
#define NTHREADS 256
#define SLOTS    432                   // 360 + 72 wrap mirror
#define MIRROR   (SLOTS - NLON_OUT)    // 72
#define ROWB     (SLOTS * 16)          // bytes per plane
#define RUNCAP   64

#define FMA4(A, c, V) { A.x = fmaf((c), (V).x, A.x); A.y = fmaf((c), (V).y, A.y); \
                        A.z = fmaf((c), (V).z, A.z); A.w = fmaf((c), (V).w, A.w); }

// ---------------- prep ----------------

// per (s,j): ptrh row sub-pointers, hbase/hlast, const-val full-row flags.
__global__ void prep1_kernel(const int* __restrict__ seg, const int* __restrict__ lat,
                             const float* __restrict__ val, int nnz,
                             int* __restrict__ ptrh, int* __restrict__ hbase,
                             int* __restrict__ hlast, int* __restrict__ flags) {
    int idx = blockIdx.x * blockDim.x + threadIdx.x;
    if (idx >= NSEG * PH) return;
    int s = idx / PH, j = idx - s * PH;
    int lo = 0, hi = nnz;
    while (lo < hi) { int m = (lo + hi) >> 1; if (seg[m] < s) lo = m + 1; else hi = m; }
    int e0 = lo;
    lo = e0; hi = nnz;
    while (lo < hi) { int m = (lo + hi) >> 1; if (seg[m] < s + 1) lo = m + 1; else hi = m; }
    int e1 = lo;
    if (e0 >= e1) {
        ptrh[idx] = e0; flags[idx] = 0;
        if (j == 0) { hbase[s] = 1 << 28; hlast[s] = -(1 << 28); }
        return;
    }
    int hb = lat[e0];
    if (j == 0) { hbase[s] = hb; hlast[s] = lat[e1 - 1]; }
    int a;
    { int tg = hb + j; lo = e0; hi = e1;
      while (lo < hi) { int m = (lo + hi) >> 1; if (lat[m] < tg) lo = m + 1; else hi = m; }
      a = lo; }
    ptrh[idx] = a;
    int f = 0;
    if (j < PH - 1) {
        int tg = hb + j + 1; lo = a; hi = e1;
        while (lo < hi) { int m = (lo + hi) >> 1; if (lat[m] < tg) lo = m + 1; else hi = m; }
        int b = lo;
        if (b - a == NLON_IN) {
            float v0 = val[a], v1 = val[a + 240], v2 = val[a + 480];
            float d = fmaxf(fabsf(v0 - v1), fmaxf(fabsf(v0 - v2), fabsf(v1 - v2)));
            f = (d < 1e-5f) ? 1 : 0;
        }
    }
    flags[idx] = f;
}

// cfb[e] = val[e]*qw[lat[e]]  (original entry order)
__global__ void cf_kernel(const int* __restrict__ lat, const float* __restrict__ val,
                          const float* __restrict__ qw, int nnz, float* __restrict__ cfb) {
    int e = blockIdx.x * blockDim.x + threadIdx.x;
    if (e < nnz) cfb[e] = val[e] * qw[lat[e]];
}

// per (s,j): build w-contiguous runs {e0, s0|odd<<9|len<<11}, chunked to 64.
__global__ void runs_kernel(const int* __restrict__ lon, const int* __restrict__ ptrh,
                            const int* __restrict__ flags,
                            int* __restrict__ runcnt, uint2* __restrict__ runslab) {
    int idx = blockIdx.x * blockDim.x + threadIdx.x;
    if (idx >= NSEG * PH) return;
    int j = idx % PH;
    if (j >= PH - 1) { runcnt[idx] = 0; return; }
    int a = ptrh[idx], b = ptrh[idx + 1];
    if (b <= a || flags[idx]) { runcnt[idx] = 0; return; }
    int cnt = 0;
    int rs = a, w0 = lon[a], wprev = w0, len = 1;
    for (int e = a + 1; e < b; ++e) {
        int w = lon[e];
        if (w == wprev + 1 && len < RUNCAP) { ++len; wprev = w; }
        else {
            int s0 = ((w0 >> 1) + NLON_OUT - 1) % NLON_OUT;
            runslab[a + cnt] = make_uint2((unsigned)rs,
                (unsigned)(s0 | ((w0 & 1) << 9) | (len << 11)));
            ++cnt; rs = e; w0 = w; wprev = w; len = 1;
        }
    }
    int s0 = ((w0 >> 1) + NLON_OUT - 1) % NLON_OUT;
    runslab[a + cnt] = make_uint2((unsigned)rs,
        (unsigned)(s0 | ((w0 & 1) << 9) | (len << 11)));
    ++cnt;
    runcnt[idx] = cnt;
}

// ---------------- main ----------------

__global__ __launch_bounds__(NTHREADS) void disco_kernel(
    const float* __restrict__ x,
    const float* __restrict__ cfb,
    const uint2* __restrict__ runslab,
    const int*   __restrict__ runcnt,
    const int*   __restrict__ ptrh,
    const int*   __restrict__ hbase,
    const int*   __restrict__ hlast,
    const int*   __restrict__ flags,
    float*       __restrict__ out)
{
    __shared__ float4 ldsx[MAXR * 2][SLOTS];   // 27,648 B
    __shared__ float4 accbuf[120][3];          //  5,760 B -> 4 blocks/CU

    const int tid      = threadIdx.x;
    const int lane     = tid & 63;
    const int wpair    = tid >> 7;             // 0: waves 0-1, 1: waves 2-3
    const int pairlane = tid & 127;
    const int pid      = (pairlane < 120) ? pairlane : pairlane - 120;
    const int p0       = 3 * pid;
    const int bc0      = blockIdx.x * G;
    const int ty       = blockIdx.y;
    const int t        = (ty & 1) ? (NLAT_OUT - 1 - (ty >> 1)) : (ty >> 1); // poles first
    const int s        = blockIdx.z * NLAT_OUT + t;
    const int hb = hbase[s], hl = hlast[s];    // empty: hb > hl

    float4 aP0 = {0.f,0.f,0.f,0.f}, aP1 = aP0, aP2 = aP0;
    const char* lb = (const char*)&ldsx[0][0];

    for (int r0 = hb; r0 <= hl; r0 += MAXR) {
        const int rn = min(MAXR, hl - r0 + 1);
        __syncthreads();                        // prior window readers done
        // ---- stage rows (4ch, parity-split, 72-slot wrap mirror) ----
        for (int r = 0; r < rn; ++r) {
            const float* xr = x + (size_t)bc0 * CHW + (size_t)(r0 + r) * NLON_IN;
            for (int m = tid; m < NLON_OUT; m += NTHREADS) {
                const float2 v0 = *(const float2*)(xr + 2 * m);
                const float2 v1 = *(const float2*)(xr + 2 * m + CHW);
                const float2 v2 = *(const float2*)(xr + 2 * m + 2 * CHW);
                const float2 v3 = *(const float2*)(xr + 2 * m + 3 * CHW);
                const float4 ev = {v0.x, v1.x, v2.x, v3.x};
                const float4 ov = {v0.y, v1.y, v2.y, v3.y};
                ldsx[2 * r + 0][m] = ev;
                ldsx[2 * r + 1][m] = ov;
                if (m < MIRROR) {
                    ldsx[2 * r + 0][NLON_OUT + m] = ev;
                    ldsx[2 * r + 1][NLON_OUT + m] = ov;
                }
            }
        }
        __syncthreads();
        // ---- rows of this window; row -> pair by (j&1) (== plane pair) ----
        for (int r = 0; r < rn; ++r) {
            const int j = (r0 + r) - hb;
            if (j < 0 || j >= PH - 1) continue;
            if ((j & 1) != wpair) continue;      // wave-uniform
            const int idx = s * PH + j;
            const int a = ptrh[idx], b = ptrh[idx + 1];
            if (a >= b) continue;
            const int rp0 = (j & 1) * 2;
            if (flags[idx]) {                    // constant-val full row: cf*rowsum
                float4 v = {0.f,0.f,0.f,0.f};
                for (int m = lane; m < NLON_OUT; m += 64) {
                    const float4 u0 = ldsx[rp0][m], u1 = ldsx[rp0 + 1][m];
                    v.x += u0.x + u1.x; v.y += u0.y + u1.y;
                    v.z += u0.z + u1.z; v.w += u0.w + u1.w;
                }
#pragma unroll
                for (int o = 32; o >= 1; o >>= 1) {
                    v.x += __shfl_xor(v.x, o); v.y += __shfl_xor(v.y, o);
                    v.z += __shfl_xor(v.z, o); v.w += __shfl_xor(v.w, o);
                }
                const float cf = cfb[a];
                FMA4(aP0, cf, v); FMA4(aP1, cf, v); FMA4(aP2, cf, v);
                continue;
            }
            const int rc = runcnt[idx];
            for (int rr = 0; rr < rc; ++rr) {
                const uint2 R = runslab[a + rr];
                const int e0  = __builtin_amdgcn_readfirstlane((int)R.x);
                const int y   = __builtin_amdgcn_readfirstlane((int)R.y);
                const int s0A = y & 511;
                const int odd = (y >> 9) & 1;
                const int len = y >> 11;
                int qA = s0A - p0 - 2; qA += (qA >> 31) & NLON_OUT;   // [0,359]
                const char* pA = lb + (size_t)(rp0 + odd) * ROWB + ((size_t)qA << 4);
                const char* pB = lb + (size_t)(rp0 + (odd ^ 1)) * ROWB
                                    + ((size_t)(qA + odd) << 4);
                float4 A0 = *(const float4*)pA;
                float4 A1 = *(const float4*)(pA + 16);
                float4 A2 = *(const float4*)(pA + 32);
                float4 B0 = *(const float4*)pB;
                float4 B1 = *(const float4*)(pB + 16);
                float4 B2 = *(const float4*)(pB + 32);
                pA += 48; pB += 48;
                const float* cfp = cfb + e0;
                int i = 0;
#pragma unroll 2
                for (; i + 2 <= len; i += 2) {
                    const float c0 = cfp[i];
                    const float c1 = cfp[i + 1];
                    const float4 nA = *(const float4*)pA; pA += 16;
                    const float4 nB = *(const float4*)pB; pB += 16;
                    FMA4(aP0, c0, A2); FMA4(aP1, c0, A1); FMA4(aP2, c0, A0);
                    A0 = A1; A1 = A2; A2 = nA;
                    FMA4(aP0, c1, B2); FMA4(aP1, c1, B1); FMA4(aP2, c1, B0);
                    B0 = B1; B1 = B2; B2 = nB;
                }
                if (i < len) {                   // odd tail (parity A)
                    const float c0 = cfp[i];
                    FMA4(aP0, c0, A2); FMA4(aP1, c0, A1); FMA4(aP2, c0, A0);
                }
            }
        }
    }

    // ---- combine pair-1 into pair-0, store ----
    __syncthreads();
    if (wpair == 1 && pairlane < 120) {
        accbuf[pid][0] = aP0; accbuf[pid][1] = aP1; accbuf[pid][2] = aP2;
    }
    __syncthreads();
    if (wpair == 0 && pairlane < 120) {
        const float4 b0 = accbuf[pid][0], b1 = accbuf[pid][1], b2 = accbuf[pid][2];
        aP0.x += b0.x; aP0.y += b0.y; aP0.z += b0.z; aP0.w += b0.w;
        aP1.x += b1.x; aP1.y += b1.y; aP1.z += b1.z; aP1.w += b1.w;
        aP2.x += b2.x; aP2.y += b2.y; aP2.z += b2.z; aP2.w += b2.w;
        const size_t cs = (size_t)NSEG * NLON_OUT;
        const size_t ob = ((size_t)bc0 * NSEG + s) * NLON_OUT + p0;
        out[ob]          = aP0.x; out[ob + 1]          = aP1.x; out[ob + 2]          = aP2.x;
        out[ob + cs]     = aP0.y; out[ob + cs + 1]     = aP1.y; out[ob + cs + 2]     = aP2.y;
        out[ob + 2*cs]   = aP0.z; out[ob + 2*cs + 1]   = aP1.z; out[ob + 2*cs + 2]   = aP2.z;
        out[ob + 3*cs]   = aP0.w; out[ob + 3*cs + 1]   = aP1.w; out[ob + 3*cs + 2]   = aP2.w;
    }
}

// ---------------- fallback (tiny ws) ----------------

__global__ void segptr_kernel(const int* __restrict__ seg, int nnz, int* __restrict__ ptr) {
    int s = blockIdx.x * blockDim.x + threadIdx.x;
    if (s > NSEG) return;
    if (s == NSEG) { ptr[NSEG] = nnz; return; }
    int lo = 0, hi = nnz;
    while (lo < hi) { int m = (lo + hi) >> 1; if (seg[m] < s) lo = m + 1; else hi = m; }
    ptr[s] = lo;
}

__global__ __launch_bounds__(384) void disco_simple_kernel(
    const float* __restrict__ x, const float* __restrict__ qw,
    const int* __restrict__ lat, const int* __restrict__ lon,
    const float* __restrict__ val, const int* __restrict__ ptr,
    float* __restrict__ out)
{
    const int p = threadIdx.x;
    if (p >= NLON_OUT) return;
    const int kt = blockIdx.x, bc0 = blockIdx.y * 8;
    const int e0 = ptr[kt], e1 = ptr[kt + 1];
    float acc[8];
#pragma unroll
    for (int g = 0; g < 8; ++g) acc[g] = 0.0f;
    const int pw = 2 * p + 2;
    const float* xb = x + (size_t)bc0 * CHW;
    for (int e = e0; e < e1; ++e) {
        const int h = lat[e], w = lon[e];
        const float cf = val[e] * qw[h];
        int col = w - pw; if (col < 0) col += NLON_IN;
        const float* src = xb + h * NLON_IN + col;
#pragma unroll
        for (int g = 0; g < 8; ++g) acc[g] = fmaf(cf, src[(size_t)g * CHW], acc[g]);
    }
    const size_t ob = ((size_t)bc0 * NSEG + kt) * NLON_OUT + p;
#pragma unroll
    for (int g = 0; g < 8; ++g) out[ob + (size_t)g * NSEG * NLON_OUT] = acc[g];
}

// ---------------- launcher ----------------

extern "C" void kernel_launch(void* const* d_in, const int* in_sizes, int n_in,
                              void* d_out, int out_size, void* d_ws, size_t ws_size,
                              hipStream_t stream)
{
    const float* x   = (const float*)d_in[0];   // [2,64,360,720] f32
    const float* qw  = (const float*)d_in[1];   // [360,1] f32
    const int*   seg = (const int*)  d_in[2];   // [nnz] i32 sorted asc
    const int*   lat = (const int*)  d_in[3];
    const int*   lon = (const int*)  d_in[4];
    const float* val = (const float*)d_in[5];
    const int    nnz = in_sizes[2];
    const int    nnzpad = (nnz + 3) & ~3;

    char* w = (char*)d_ws;
    size_t off = 0;
    int* ptrh   = (int*)(w + off); off += (size_t)NSEG * PH * 4;   // 21600
    int* hbase  = (int*)(w + off); off += NSEG * 4;                // 2160
    int* hlast  = (int*)(w + off); off += NSEG * 4;                // 2160
    int* flags  = (int*)(w + off); off += (size_t)NSEG * PH * 4;   // 21600
    int* runcnt = (int*)(w + off); off += (size_t)NSEG * PH * 4;   // 21600 -> 69120
    float* cfb  = (float*)(w + off); off += (size_t)nnzpad * 4;
    off = (off + 7) & ~(size_t)7;
    uint2* runslab = (uint2*)(w + off); off += (size_t)nnz * 8;

    if (ws_size < off) {                         // tiny ws: slow-but-correct path
        int* ptr = (int*)d_ws;
        segptr_kernel<<<(NSEG + 1 + 255) / 256, 256, 0, stream>>>(seg, nnz, ptr);
        dim3 grid(NSEG, BCTOT / 8);
        disco_simple_kernel<<<grid, 384, 0, stream>>>(x, qw, lat, lon, val, ptr,
                                                      (float*)d_out);
        return;
    }

    prep1_kernel<<<(NSEG * PH + 255) / 256, 256, 0, stream>>>(seg, lat, val, nnz,
                                                              ptrh, hbase, hlast, flags);
    cf_kernel<<<(nnz + 255) / 256, 256, 0, stream>>>(lat, val, qw, nnz, cfb);
    runs_kernel<<<(NSEG * PH + 255) / 256, 256, 0, stream>>>(lon, ptrh, flags,
                                                             runcnt, runslab);

    dim3 grid(NBCG, NLAT_OUT, KSIZE);
    disco_kernel<<<grid, NTHREADS, 0, stream>>>(x, cfb, runslab, runcnt,
                                                ptrh, hbase, hlast, flags,
                                                (float*)d_out);
}

// Round 10
// 183.231 us; speedup vs baseline: 1.5302x; 1.5302x over previous
//
#include <hip/hip_runtime.h>

// DISCO S2 conv, equiangular 360x720 -> 180x360, K=3, B*C=128.
// out[bc, k*180+t, p] = sum_{e in seg(k,t)} val[e]*qw[lat[e]] * x[bc, lat[e], (lon[e]-2p-2) mod 720]
//
// Round-10:
//  - wave-parallel run builder (ballot/ffs/popc) replaces the serial per-row
//    scan that cost ~80 us of prep in round 9.
//  - hot loop: p-blocking PB=3 kept, but the depth-3 sliding window is now a
//    hand-unrolled period-8 body with 4-name register rotation (no v_mov
//    shifts) and v_pk_fma_f32 packed FP32 FMAs (6 pk ops per entry-lane
//    instead of 12 fmac). Window slots read as 2x ds_read_b64 (v2f).
//  - runs are <=64 entries (chunk-aligned); tail <8 uses direct reads.
//  - pole constant-val full rows collapse to wave-local rowsum.

#define NLAT_IN  360
#define NLON_IN  720
#define NLAT_OUT 180
#define NLON_OUT 360
#define KSIZE    3
#define NSEG     (KSIZE * NLAT_OUT)    // 540
#define CHW      (NLAT_IN * NLON_IN)   // 259200
#define BCTOT    128
#define G        4
#define NBCG     (BCTOT / G)           // 32
#define MAXR     2
#define PH       10
#define NTHREADS 256
#define SLOTS    432                   // 360 + 72 wrap mirror
#define MIRROR   (SLOTS - NLON_OUT)    // 72
#define ROWB     (SLOTS * 16)          // bytes per parity plane

typedef float v2f __attribute__((ext_vector_type(2)));

__device__ __forceinline__ void PKF(v2f& a, v2f x, v2f c) {
    asm("v_pk_fma_f32 %0, %1, %2, %0" : "+v"(a) : "v"(x), "v"(c));
}

// ---------------- prep ----------------

// per (s,j): ptrh row sub-pointers, hbase/hlast, const-val full-row flags.
__global__ void prep1_kernel(const int* __restrict__ seg, const int* __restrict__ lat,
                             const float* __restrict__ val, int nnz,
                             int* __restrict__ ptrh, int* __restrict__ hbase,
                             int* __restrict__ hlast, int* __restrict__ flags) {
    int idx = blockIdx.x * blockDim.x + threadIdx.x;
    if (idx >= NSEG * PH) return;
    int s = idx / PH, j = idx - s * PH;
    int lo = 0, hi = nnz;
    while (lo < hi) { int m = (lo + hi) >> 1; if (seg[m] < s) lo = m + 1; else hi = m; }
    int e0 = lo;
    lo = e0; hi = nnz;
    while (lo < hi) { int m = (lo + hi) >> 1; if (seg[m] < s + 1) lo = m + 1; else hi = m; }
    int e1 = lo;
    if (e0 >= e1) {
        ptrh[idx] = e0; flags[idx] = 0;
        if (j == 0) { hbase[s] = 1 << 28; hlast[s] = -(1 << 28); }
        return;
    }
    int hb = lat[e0];
    if (j == 0) { hbase[s] = hb; hlast[s] = lat[e1 - 1]; }
    int a;
    { int tg = hb + j; lo = e0; hi = e1;
      while (lo < hi) { int m = (lo + hi) >> 1; if (lat[m] < tg) lo = m + 1; else hi = m; }
      a = lo; }
    ptrh[idx] = a;
    int f = 0;
    if (j < PH - 1) {
        int tg = hb + j + 1; lo = a; hi = e1;
        while (lo < hi) { int m = (lo + hi) >> 1; if (lat[m] < tg) lo = m + 1; else hi = m; }
        int b = lo;
        if (b - a == NLON_IN) {
            float v0 = val[a], v1 = val[a + 240], v2 = val[a + 480];
            float d = fmaxf(fabsf(v0 - v1), fmaxf(fabsf(v0 - v2), fabsf(v1 - v2)));
            f = (d < 1e-5f) ? 1 : 0;
        }
    }
    flags[idx] = f;
}

// cfb[e] = val[e]*qw[lat[e]]  (original entry order)
__global__ void cf_kernel(const int* __restrict__ lat, const float* __restrict__ val,
                          const float* __restrict__ qw, int nnz, float* __restrict__ cfb) {
    int e = blockIdx.x * blockDim.x + threadIdx.x;
    if (e < nnz) cfb[e] = val[e] * qw[lat[e]];
}

// wave-parallel run builder: one wave per (s,j) row; 64-entry chunks;
// run start = chunk start or lon discontinuity; record {e0, s0|odd<<9|len<<11}.
__global__ void runs_kernel(const int* __restrict__ lon, const int* __restrict__ ptrh,
                            const int* __restrict__ flags,
                            int* __restrict__ runcnt, uint2* __restrict__ runslab) {
    const int idx  = blockIdx.x * 4 + (threadIdx.x >> 6);
    if (idx >= NSEG * PH) return;
    const int lane = threadIdx.x & 63;
    const int j = idx % PH;
    int runbase = 0;
    if (j < PH - 1) {
        const int a = ptrh[idx], b = ptrh[idx + 1];
        if (b > a && !flags[idx]) {
            for (int c = a; c < b; c += 64) {
                const int e = c + lane;
                const bool active = e < b;
                const int w   = active ? lon[e] : 0;
                const int wm1 = (active && e > a) ? lon[e - 1] : -99;
                const bool isStart = active && (lane == 0 || w != wm1 + 1);
                const unsigned long long mask = __ballot(isStart);
                if (isStart) {
                    const int cnt = min(64, b - c);
                    unsigned long long hv = (mask >> lane) >> 1;  // bits above lane
                    const int len = hv ? __ffsll((long long)hv) : (cnt - lane);
                    const int cidx = __popcll(mask & ((1ull << lane) - 1ull));
                    const int s0 = ((w >> 1) + NLON_OUT - 1) % NLON_OUT;
                    runslab[a + runbase + cidx] = make_uint2(
                        (unsigned)e, (unsigned)(s0 | ((w & 1) << 9) | (len << 11)));
                }
                runbase += __popcll(mask);
            }
        }
    }
    if (lane == 0) runcnt[idx] = runbase;
}

// ---------------- main ----------------

__global__ __launch_bounds__(NTHREADS) void disco_kernel(
    const float* __restrict__ x,
    const float* __restrict__ cfb,
    const uint2* __restrict__ runslab,
    const int*   __restrict__ runcnt,
    const int*   __restrict__ ptrh,
    const int*   __restrict__ hbase,
    const int*   __restrict__ hlast,
    const int*   __restrict__ flags,
    float*       __restrict__ out)
{
    __shared__ float4 ldsx[MAXR * 2][SLOTS];   // 27,648 B
    __shared__ v2f    accbuf[120][6];          //  5,760 B -> 4 blocks/CU

    const int tid      = threadIdx.x;
    const int lane     = tid & 63;
    const int wpair    = tid >> 7;             // 0: waves 0-1, 1: waves 2-3
    const int pairlane = tid & 127;
    const int pid      = (pairlane < 120) ? pairlane : pairlane - 120;
    const int p0       = 3 * pid;
    const int bc0      = blockIdx.x * G;
    const int ty       = blockIdx.y;
    const int t        = (ty & 1) ? (NLAT_OUT - 1 - (ty >> 1)) : (ty >> 1); // poles first
    const int s        = blockIdx.z * NLAT_OUT + t;
    const int hb = hbase[s], hl = hlast[s];    // empty: hb > hl

    v2f a0l = {0.f, 0.f}, a0h = a0l, a1l = a0l, a1h = a0l, a2l = a0l, a2h = a0l;
    const char* lb = (const char*)&ldsx[0][0];

    for (int r0 = hb; r0 <= hl; r0 += MAXR) {
        const int rn = min(MAXR, hl - r0 + 1);
        __syncthreads();                        // prior window readers done
        // ---- stage rows (4ch, parity-split, 72-slot wrap mirror) ----
        for (int r = 0; r < rn; ++r) {
            const float* xr = x + (size_t)bc0 * CHW + (size_t)(r0 + r) * NLON_IN;
            for (int m = tid; m < NLON_OUT; m += NTHREADS) {
                const float2 v0 = *(const float2*)(xr + 2 * m);
                const float2 v1 = *(const float2*)(xr + 2 * m + CHW);
                const float2 v2 = *(const float2*)(xr + 2 * m + 2 * CHW);
                const float2 v3 = *(const float2*)(xr + 2 * m + 3 * CHW);
                const float4 ev = {v0.x, v1.x, v2.x, v3.x};
                const float4 ov = {v0.y, v1.y, v2.y, v3.y};
                ldsx[2 * r + 0][m] = ev;
                ldsx[2 * r + 1][m] = ov;
                if (m < MIRROR) {
                    ldsx[2 * r + 0][NLON_OUT + m] = ev;
                    ldsx[2 * r + 1][NLON_OUT + m] = ov;
                }
            }
        }
        __syncthreads();
        // ---- rows of this window; row -> pair by (j&1) ----
        for (int r = 0; r < rn; ++r) {
            const int j = (r0 + r) - hb;
            if (j < 0 || j >= PH - 1) continue;
            if ((j & 1) != wpair) continue;      // wave-uniform
            const int idx = s * PH + j;
            const int a = ptrh[idx], b = ptrh[idx + 1];
            if (a >= b) continue;
            const int rp0 = (j & 1) * 2;
            if (flags[idx]) {                    // constant-val full row: cf*rowsum
                float4 v = {0.f, 0.f, 0.f, 0.f};
                for (int m = lane; m < NLON_OUT; m += 64) {
                    const float4 u0 = ldsx[rp0][m], u1 = ldsx[rp0 + 1][m];
                    v.x += u0.x + u1.x; v.y += u0.y + u1.y;
                    v.z += u0.z + u1.z; v.w += u0.w + u1.w;
                }
#pragma unroll
                for (int o = 32; o >= 1; o >>= 1) {
                    v.x += __shfl_xor(v.x, o); v.y += __shfl_xor(v.y, o);
                    v.z += __shfl_xor(v.z, o); v.w += __shfl_xor(v.w, o);
                }
                const float cf = cfb[a];
                a0l.x = fmaf(cf, v.x, a0l.x); a0l.y = fmaf(cf, v.y, a0l.y);
                a0h.x = fmaf(cf, v.z, a0h.x); a0h.y = fmaf(cf, v.w, a0h.y);
                a1l.x = fmaf(cf, v.x, a1l.x); a1l.y = fmaf(cf, v.y, a1l.y);
                a1h.x = fmaf(cf, v.z, a1h.x); a1h.y = fmaf(cf, v.w, a1h.y);
                a2l.x = fmaf(cf, v.x, a2l.x); a2l.y = fmaf(cf, v.y, a2l.y);
                a2h.x = fmaf(cf, v.z, a2h.x); a2h.y = fmaf(cf, v.w, a2h.y);
                continue;
            }
            const int rc = runcnt[idx];
            for (int rr = 0; rr < rc; ++rr) {
                const uint2 R = runslab[a + rr];
                const int e0  = __builtin_amdgcn_readfirstlane((int)R.x);
                const int y   = __builtin_amdgcn_readfirstlane((int)R.y);
                const int s0A = y & 511;
                const int odd = (y >> 9) & 1;
                const int len = y >> 11;
                int qA = s0A - p0 - 2; qA += (qA >> 31) & NLON_OUT;   // [0,359]
                const char* baseA = lb + (size_t)(rp0 + odd) * ROWB + ((size_t)qA << 4);
                const char* baseB = lb + (size_t)(rp0 + (odd ^ 1)) * ROWB
                                       + ((size_t)(qA + odd) << 4);
                const float* cfp = cfb + e0;
                int i = 0;
                if (len >= 8) {
                    // window init: 3 slots per parity
                    v2f A0l = *(const v2f*)(baseA +  0), A0h = *(const v2f*)(baseA +  8);
                    v2f A1l = *(const v2f*)(baseA + 16), A1h = *(const v2f*)(baseA + 24);
                    v2f A2l = *(const v2f*)(baseA + 32), A2h = *(const v2f*)(baseA + 40);
                    v2f B0l = *(const v2f*)(baseB +  0), B0h = *(const v2f*)(baseB +  8);
                    v2f B1l = *(const v2f*)(baseB + 16), B1h = *(const v2f*)(baseB + 24);
                    v2f B2l = *(const v2f*)(baseB + 32), B2h = *(const v2f*)(baseB + 40);
                    v2f A3l, A3h, B3l, B3h;
                    const char* ldA = baseA + 48;
                    const char* ldB = baseB + 48;
                    for (; i + 8 <= len; i += 8) {
                        float cs; v2f c;
                        // A#0: (A0,A1,A2) -> (aP2,aP1,aP0); load A3
                        A3l = *(const v2f*)(ldA); A3h = *(const v2f*)(ldA + 8); ldA += 16;
                        cs = cfp[i + 0]; c = (v2f){cs, cs};
                        PKF(a2l, A0l, c); PKF(a2h, A0h, c);
                        PKF(a1l, A1l, c); PKF(a1h, A1h, c);
                        PKF(a0l, A2l, c); PKF(a0h, A2h, c);
                        // B#0
                        B3l = *(const v2f*)(ldB); B3h = *(const v2f*)(ldB + 8); ldB += 16;
                        cs = cfp[i + 1]; c = (v2f){cs, cs};
                        PKF(a2l, B0l, c); PKF(a2h, B0h, c);
                        PKF(a1l, B1l, c); PKF(a1h, B1h, c);
                        PKF(a0l, B2l, c); PKF(a0h, B2h, c);
                        // A#1: (A1,A2,A3); load A0
                        A0l = *(const v2f*)(ldA); A0h = *(const v2f*)(ldA + 8); ldA += 16;
                        cs = cfp[i + 2]; c = (v2f){cs, cs};
                        PKF(a2l, A1l, c); PKF(a2h, A1h, c);
                        PKF(a1l, A2l, c); PKF(a1h, A2h, c);
                        PKF(a0l, A3l, c); PKF(a0h, A3h, c);
                        // B#1
                        B0l = *(const v2f*)(ldB); B0h = *(const v2f*)(ldB + 8); ldB += 16;
                        cs = cfp[i + 3]; c = (v2f){cs, cs};
                        PKF(a2l, B1l, c); PKF(a2h, B1h, c);
                        PKF(a1l, B2l, c); PKF(a1h, B2h, c);
                        PKF(a0l, B3l, c); PKF(a0h, B3h, c);
                        // A#2: (A2,A3,A0); load A1
                        A1l = *(const v2f*)(ldA); A1h = *(const v2f*)(ldA + 8); ldA += 16;
                        cs = cfp[i + 4]; c = (v2f){cs, cs};
                        PKF(a2l, A2l, c); PKF(a2h, A2h, c);
                        PKF(a1l, A3l, c); PKF(a1h, A3h, c);
                        PKF(a0l, A0l, c); PKF(a0h, A0h, c);
                        // B#2
                        B1l = *(const v2f*)(ldB); B1h = *(const v2f*)(ldB + 8); ldB += 16;
                        cs = cfp[i + 5]; c = (v2f){cs, cs};
                        PKF(a2l, B2l, c); PKF(a2h, B2h, c);
                        PKF(a1l, B3l, c); PKF(a1h, B3h, c);
                        PKF(a0l, B0l, c); PKF(a0h, B0h, c);
                        // A#3: (A3,A0,A1); load A2
                        A2l = *(const v2f*)(ldA); A2h = *(const v2f*)(ldA + 8); ldA += 16;
                        cs = cfp[i + 6]; c = (v2f){cs, cs};
                        PKF(a2l, A3l, c); PKF(a2h, A3h, c);
                        PKF(a1l, A0l, c); PKF(a1h, A0h, c);
                        PKF(a0l, A1l, c); PKF(a0h, A1h, c);
                        // B#3
                        B2l = *(const v2f*)(ldB); B2h = *(const v2f*)(ldB + 8); ldB += 16;
                        cs = cfp[i + 7]; c = (v2f){cs, cs};
                        PKF(a2l, B3l, c); PKF(a2h, B3h, c);
                        PKF(a1l, B0l, c); PKF(a1h, B0h, c);
                        PKF(a0l, B1l, c); PKF(a0h, B1h, c);
                    }
                }
                // tail (<8 entries, or whole short run): direct addressed reads
                for (; i < len; ++i) {
                    const int m = i >> 1;
                    const char* bp = (i & 1) ? (baseB + ((size_t)m << 4))
                                             : (baseA + ((size_t)m << 4));
                    const float cs = cfp[i]; const v2f c = (v2f){cs, cs};
                    const v2f w0l = *(const v2f*)(bp +  0), w0h = *(const v2f*)(bp +  8);
                    const v2f w1l = *(const v2f*)(bp + 16), w1h = *(const v2f*)(bp + 24);
                    const v2f w2l = *(const v2f*)(bp + 32), w2h = *(const v2f*)(bp + 40);
                    PKF(a2l, w0l, c); PKF(a2h, w0h, c);
                    PKF(a1l, w1l, c); PKF(a1h, w1h, c);
                    PKF(a0l, w2l, c); PKF(a0h, w2h, c);
                }
            }
        }
    }

    // ---- combine pair-1 into pair-0, store ----
    __syncthreads();
    if (wpair == 1 && pairlane < 120) {
        accbuf[pid][0] = a0l; accbuf[pid][1] = a0h;
        accbuf[pid][2] = a1l; accbuf[pid][3] = a1h;
        accbuf[pid][4] = a2l; accbuf[pid][5] = a2h;
    }
    __syncthreads();
    if (wpair == 0 && pairlane < 120) {
        a0l += accbuf[pid][0]; a0h += accbuf[pid][1];
        a1l += accbuf[pid][2]; a1h += accbuf[pid][3];
        a2l += accbuf[pid][4]; a2h += accbuf[pid][5];
        const size_t cs_ = (size_t)NSEG * NLON_OUT;
        const size_t ob  = ((size_t)bc0 * NSEG + s) * NLON_OUT + p0;
        out[ob]              = a0l.x; out[ob + 1]              = a1l.x; out[ob + 2]              = a2l.x;
        out[ob + cs_]        = a0l.y; out[ob + cs_ + 1]        = a1l.y; out[ob + cs_ + 2]        = a2l.y;
        out[ob + 2 * cs_]    = a0h.x; out[ob + 2 * cs_ + 1]    = a1h.x; out[ob + 2 * cs_ + 2]    = a2h.x;
        out[ob + 3 * cs_]    = a0h.y; out[ob + 3 * cs_ + 1]    = a1h.y; out[ob + 3 * cs_ + 2]    = a2h.y;
    }
}

// ---------------- fallback (tiny ws) ----------------

__global__ void segptr_kernel(const int* __restrict__ seg, int nnz, int* __restrict__ ptr) {
    int s = blockIdx.x * blockDim.x + threadIdx.x;
    if (s > NSEG) return;
    if (s == NSEG) { ptr[NSEG] = nnz; return; }
    int lo = 0, hi = nnz;
    while (lo < hi) { int m = (lo + hi) >> 1; if (seg[m] < s) lo = m + 1; else hi = m; }
    ptr[s] = lo;
}

__global__ __launch_bounds__(384) void disco_simple_kernel(
    const float* __restrict__ x, const float* __restrict__ qw,
    const int* __restrict__ lat, const int* __restrict__ lon,
    const float* __restrict__ val, const int* __restrict__ ptr,
    float* __restrict__ out)
{
    const int p = threadIdx.x;
    if (p >= NLON_OUT) return;
    const int kt = blockIdx.x, bc0 = blockIdx.y * 8;
    const int e0 = ptr[kt], e1 = ptr[kt + 1];
    float acc[8];
#pragma unroll
    for (int g = 0; g < 8; ++g) acc[g] = 0.0f;
    const int pw = 2 * p + 2;
    const float* xb = x + (size_t)bc0 * CHW;
    for (int e = e0; e < e1; ++e) {
        const int h = lat[e], w = lon[e];
        const float cf = val[e] * qw[h];
        int col = w - pw; if (col < 0) col += NLON_IN;
        const float* src = xb + h * NLON_IN + col;
#pragma unroll
        for (int g = 0; g < 8; ++g) acc[g] = fmaf(cf, src[(size_t)g * CHW], acc[g]);
    }
    const size_t ob = ((size_t)bc0 * NSEG + kt) * NLON_OUT + p;
#pragma unroll
    for (int g = 0; g < 8; ++g) out[ob + (size_t)g * NSEG * NLON_OUT] = acc[g];
}

// ---------------- launcher ----------------

extern "C" void kernel_launch(void* const* d_in, const int* in_sizes, int n_in,
                              void* d_out, int out_size, void* d_ws, size_t ws_size,
                              hipStream_t stream)
{
    const float* x   = (const float*)d_in[0];   // [2,64,360,720] f32
    const float* qw  = (const float*)d_in[1];   // [360,1] f32
    const int*   seg = (const int*)  d_in[2];   // [nnz] i32 sorted asc
    const int*   lat = (const int*)  d_in[3];
    const int*   lon = (const int*)  d_in[4];
    const float* val = (const float*)d_in[5];
    const int    nnz = in_sizes[2];
    const int    nnzpad = (nnz + 3) & ~3;

    char* w = (char*)d_ws;
    size_t off = 0;
    int* ptrh   = (int*)(w + off); off += (size_t)NSEG * PH * 4;   // 21600
    int* hbase  = (int*)(w + off); off += NSEG * 4;                // 2160
    int* hlast  = (int*)(w + off); off += NSEG * 4;                // 2160
    int* flags  = (int*)(w + off); off += (size_t)NSEG * PH * 4;   // 21600
    int* runcnt = (int*)(w + off); off += (size_t)NSEG * PH * 4;   // 21600 -> 69120
    float* cfb  = (float*)(w + off); off += (size_t)nnzpad * 4;
    off = (off + 7) & ~(size_t)7;
    uint2* runslab = (uint2*)(w + off); off += (size_t)nnz * 8;

    if (ws_size < off) {                         // tiny ws: slow-but-correct path
        int* ptr = (int*)d_ws;
        segptr_kernel<<<(NSEG + 1 + 255) / 256, 256, 0, stream>>>(seg, nnz, ptr);
        dim3 grid(NSEG, BCTOT / 8);
        disco_simple_kernel<<<grid, 384, 0, stream>>>(x, qw, lat, lon, val, ptr,
                                                      (float*)d_out);
        return;
    }

    prep1_kernel<<<(NSEG * PH + 255) / 256, 256, 0, stream>>>(seg, lat, val, nnz,
                                                              ptrh, hbase, hlast, flags);
    cf_kernel<<<(nnz + 255) / 256, 256, 0, stream>>>(lat, val, qw, nnz, cfb);
    runs_kernel<<<(NSEG * PH + 3) / 4, 256, 0, stream>>>(lon, ptrh, flags,
                                                         runcnt, runslab);

    dim3 grid(NBCG, NLAT_OUT, KSIZE);
    disco_kernel<<<grid, NTHREADS, 0, stream>>>(x, cfb, runslab, runcnt,
                                                ptrh, hbase, hlast, flags,
                                                (float*)d_out);
}

// Round 11
// 152.931 us; speedup vs baseline: 1.8334x; 1.1981x over previous
//
#include <hip/hip_runtime.h>

// DISCO S2 conv, equiangular 360x720 -> 180x360, K=3, B*C=128.
// out[bc, k*180+t, p] = sum_{e in seg(k,t)} val[e]*qw[lat[e]] * x[bc, lat[e], (lon[e]-2p-2) mod 720]
//
// Round-11: T14 async-STAGE split on the round-10 kernel.
//  - staging split into {issue global->reg} (early, before compute of the
//    previous window) and {vmcnt + ds_write} (late, after the barrier).
//    L2/HBM latency of window w+1 hides under compute of window w.
//  - everything else as round-10: run-compressed entries, PB=3 sliding
//    register window, v_pk_fma_f32, wave-parallel run builder, pole
//    constant-val rowsum collapse, (bcg, t, k) grid with poles first.

#define NLAT_IN  360
#define NLON_IN  720
#define NLAT_OUT 180
#define NLON_OUT 360
#define KSIZE    3
#define NSEG     (KSIZE * NLAT_OUT)    // 540
#define CHW      (NLAT_IN * NLON_IN)   // 259200
#define BCTOT    128
#define G        4
#define NBCG     (BCTOT / G)           // 32
#define MAXR     2
#define PH       10
#define NTHREADS 256
#define SLOTS    432                   // 360 + 72 wrap mirror
#define MIRROR   (SLOTS - NLON_OUT)    // 72
#define ROWB     (SLOTS * 16)          // bytes per parity plane
#define SWI      3                     // staging items per thread (720/256)

typedef float v2f __attribute__((ext_vector_type(2)));

__device__ __forceinline__ void PKF(v2f& a, v2f x, v2f c) {
    asm("v_pk_fma_f32 %0, %1, %2, %0" : "+v"(a) : "v"(x), "v"(c));
}

// ---------------- prep ----------------

__global__ void prep1_kernel(const int* __restrict__ seg, const int* __restrict__ lat,
                             const float* __restrict__ val, int nnz,
                             int* __restrict__ ptrh, int* __restrict__ hbase,
                             int* __restrict__ hlast, int* __restrict__ flags) {
    int idx = blockIdx.x * blockDim.x + threadIdx.x;
    if (idx >= NSEG * PH) return;
    int s = idx / PH, j = idx - s * PH;
    int lo = 0, hi = nnz;
    while (lo < hi) { int m = (lo + hi) >> 1; if (seg[m] < s) lo = m + 1; else hi = m; }
    int e0 = lo;
    lo = e0; hi = nnz;
    while (lo < hi) { int m = (lo + hi) >> 1; if (seg[m] < s + 1) lo = m + 1; else hi = m; }
    int e1 = lo;
    if (e0 >= e1) {
        ptrh[idx] = e0; flags[idx] = 0;
        if (j == 0) { hbase[s] = 1 << 28; hlast[s] = -(1 << 28); }
        return;
    }
    int hb = lat[e0];
    if (j == 0) { hbase[s] = hb; hlast[s] = lat[e1 - 1]; }
    int a;
    { int tg = hb + j; lo = e0; hi = e1;
      while (lo < hi) { int m = (lo + hi) >> 1; if (lat[m] < tg) lo = m + 1; else hi = m; }
      a = lo; }
    ptrh[idx] = a;
    int f = 0;
    if (j < PH - 1) {
        int tg = hb + j + 1; lo = a; hi = e1;
        while (lo < hi) { int m = (lo + hi) >> 1; if (lat[m] < tg) lo = m + 1; else hi = m; }
        int b = lo;
        if (b - a == NLON_IN) {
            float v0 = val[a], v1 = val[a + 240], v2 = val[a + 480];
            float d = fmaxf(fabsf(v0 - v1), fmaxf(fabsf(v0 - v2), fabsf(v1 - v2)));
            f = (d < 1e-5f) ? 1 : 0;
        }
    }
    flags[idx] = f;
}

__global__ void cf_kernel(const int* __restrict__ lat, const float* __restrict__ val,
                          const float* __restrict__ qw, int nnz, float* __restrict__ cfb) {
    int e = blockIdx.x * blockDim.x + threadIdx.x;
    if (e < nnz) cfb[e] = val[e] * qw[lat[e]];
}

// wave-parallel run builder: one wave per (s,j) row; 64-entry chunks.
__global__ void runs_kernel(const int* __restrict__ lon, const int* __restrict__ ptrh,
                            const int* __restrict__ flags,
                            int* __restrict__ runcnt, uint2* __restrict__ runslab) {
    const int idx  = blockIdx.x * 4 + (threadIdx.x >> 6);
    if (idx >= NSEG * PH) return;
    const int lane = threadIdx.x & 63;
    const int j = idx % PH;
    int runbase = 0;
    if (j < PH - 1) {
        const int a = ptrh[idx], b = ptrh[idx + 1];
        if (b > a && !flags[idx]) {
            for (int c = a; c < b; c += 64) {
                const int e = c + lane;
                const bool active = e < b;
                const int w   = active ? lon[e] : 0;
                const int wm1 = (active && e > a) ? lon[e - 1] : -99;
                const bool isStart = active && (lane == 0 || w != wm1 + 1);
                const unsigned long long mask = __ballot(isStart);
                if (isStart) {
                    const int cnt = min(64, b - c);
                    unsigned long long hv = (mask >> lane) >> 1;
                    const int len = hv ? __ffsll((long long)hv) : (cnt - lane);
                    const int cidx = __popcll(mask & ((1ull << lane) - 1ull));
                    const int s0 = ((w >> 1) + NLON_OUT - 1) % NLON_OUT;
                    runslab[a + runbase + cidx] = make_uint2(
                        (unsigned)e, (unsigned)(s0 | ((w & 1) << 9) | (len << 11)));
                }
                runbase += __popcll(mask);
            }
        }
    }
    if (lane == 0) runcnt[idx] = runbase;
}

// ---------------- main ----------------

__global__ __launch_bounds__(NTHREADS) void disco_kernel(
    const float* __restrict__ x,
    const float* __restrict__ cfb,
    const uint2* __restrict__ runslab,
    const int*   __restrict__ runcnt,
    const int*   __restrict__ ptrh,
    const int*   __restrict__ hbase,
    const int*   __restrict__ hlast,
    const int*   __restrict__ flags,
    float*       __restrict__ out)
{
    __shared__ float4 ldsx[MAXR * 2][SLOTS];   // 27,648 B
    __shared__ v2f    accbuf[120][6];          //  5,760 B -> 4 blocks/CU

    const int tid      = threadIdx.x;
    const int lane     = tid & 63;
    const int wpair    = tid >> 7;
    const int pairlane = tid & 127;
    const int pid      = (pairlane < 120) ? pairlane : pairlane - 120;
    const int p0       = 3 * pid;
    const int bc0      = blockIdx.x * G;
    const int ty       = blockIdx.y;
    const int t        = (ty & 1) ? (NLAT_OUT - 1 - (ty >> 1)) : (ty >> 1); // poles first
    const int s        = blockIdx.z * NLAT_OUT + t;
    const int hb = hbase[s], hl = hlast[s];    // empty: hb > hl

    v2f a0l = {0.f, 0.f}, a0h = a0l, a1l = a0l, a1h = a0l, a2l = a0l, a2h = a0l;
    const char* lb = (const char*)&ldsx[0][0];

    // staging registers: item i covers (r, m) with idx = tid + 256*i
    float2 sv0[4], sv1[4], sv2[4];
    const float* xb = x + (size_t)bc0 * CHW;

#define LOADW(R0)                                                              \
    {                                                                          \
        {   const int idx_ = tid;            /* i = 0, always < 720 */         \
            const int rr_ = idx_ >= 360;                                       \
            const int m_  = idx_ - 360 * rr_;                                  \
            const int row_ = min((R0) + rr_, hl);                              \
            const float* xr_ = xb + (size_t)row_ * NLON_IN + 2 * m_;           \
            sv0[0] = *(const float2*)(xr_);                                    \
            sv0[1] = *(const float2*)(xr_ + CHW);                              \
            sv0[2] = *(const float2*)(xr_ + 2 * CHW);                          \
            sv0[3] = *(const float2*)(xr_ + 3 * CHW);                          \
        }                                                                      \
        {   const int idx_ = tid + 256;      /* i = 1, always < 720 */         \
            const int rr_ = idx_ >= 360;                                       \
            const int m_  = idx_ - 360 * rr_;                                  \
            const int row_ = min((R0) + rr_, hl);                              \
            const float* xr_ = xb + (size_t)row_ * NLON_IN + 2 * m_;           \
            sv1[0] = *(const float2*)(xr_);                                    \
            sv1[1] = *(const float2*)(xr_ + CHW);                              \
            sv1[2] = *(const float2*)(xr_ + 2 * CHW);                          \
            sv1[3] = *(const float2*)(xr_ + 3 * CHW);                          \
        }                                                                      \
        if (tid < 208) {                     /* i = 2: idx < 720 */            \
            const int idx_ = tid + 512;                                        \
            const int rr_ = 1;                                                 \
            const int m_  = idx_ - 360;                                        \
            const int row_ = min((R0) + rr_, hl);                              \
            const float* xr_ = xb + (size_t)row_ * NLON_IN + 2 * m_;           \
            sv2[0] = *(const float2*)(xr_);                                    \
            sv2[1] = *(const float2*)(xr_ + CHW);                              \
            sv2[2] = *(const float2*)(xr_ + 2 * CHW);                          \
            sv2[3] = *(const float2*)(xr_ + 3 * CHW);                          \
        }                                                                      \
    }

#define WRITEW()                                                               \
    {                                                                          \
        {   const int idx_ = tid;                                              \
            const int rr_ = idx_ >= 360;                                       \
            const int m_  = idx_ - 360 * rr_;                                  \
            const float4 ev_ = {sv0[0].x, sv0[1].x, sv0[2].x, sv0[3].x};       \
            const float4 ov_ = {sv0[0].y, sv0[1].y, sv0[2].y, sv0[3].y};       \
            ldsx[2 * rr_ + 0][m_] = ev_;                                       \
            ldsx[2 * rr_ + 1][m_] = ov_;                                       \
            if (m_ < MIRROR) {                                                 \
                ldsx[2 * rr_ + 0][NLON_OUT + m_] = ev_;                        \
                ldsx[2 * rr_ + 1][NLON_OUT + m_] = ov_;                        \
            }                                                                  \
        }                                                                      \
        {   const int idx_ = tid + 256;                                        \
            const int rr_ = idx_ >= 360;                                       \
            const int m_  = idx_ - 360 * rr_;                                  \
            const float4 ev_ = {sv1[0].x, sv1[1].x, sv1[2].x, sv1[3].x};       \
            const float4 ov_ = {sv1[0].y, sv1[1].y, sv1[2].y, sv1[3].y};       \
            ldsx[2 * rr_ + 0][m_] = ev_;                                       \
            ldsx[2 * rr_ + 1][m_] = ov_;                                       \
            if (m_ < MIRROR) {                                                 \
                ldsx[2 * rr_ + 0][NLON_OUT + m_] = ev_;                        \
                ldsx[2 * rr_ + 1][NLON_OUT + m_] = ov_;                        \
            }                                                                  \
        }                                                                      \
        if (tid < 208) {                                                       \
            const int m_ = tid + 512 - 360;                                    \
            const float4 ev_ = {sv2[0].x, sv2[1].x, sv2[2].x, sv2[3].x};       \
            const float4 ov_ = {sv2[0].y, sv2[1].y, sv2[2].y, sv2[3].y};       \
            ldsx[2][m_] = ev_;                                                 \
            ldsx[3][m_] = ov_;                                                 \
            if (m_ < MIRROR) {                                                 \
                ldsx[2][NLON_OUT + m_] = ev_;                                  \
                ldsx[3][NLON_OUT + m_] = ov_;                                  \
            }                                                                  \
        }                                                                      \
    }

    if (hb <= hl) {
        LOADW(hb);                              // prologue: first window in flight
        for (int r0 = hb; r0 <= hl; r0 += MAXR) {
            const int rn = min(MAXR, hl - r0 + 1);
            __syncthreads();                    // readers of previous window done
            WRITEW();                           // vmcnt wait happens here (hidden)
            if (r0 + MAXR <= hl) LOADW(r0 + MAXR);   // issue next window early
            __syncthreads();                    // LDS ready
            // ---- compute window ----
            for (int r = 0; r < rn; ++r) {
                const int j = (r0 + r) - hb;
                if (j < 0 || j >= PH - 1) continue;
                if ((j & 1) != wpair) continue;  // wave-uniform
                const int idx = s * PH + j;
                const int a = ptrh[idx], b = ptrh[idx + 1];
                if (a >= b) continue;
                const int rp0 = (j & 1) * 2;
                if (flags[idx]) {                // constant-val full row: cf*rowsum
                    float4 v = {0.f, 0.f, 0.f, 0.f};
                    for (int m = lane; m < NLON_OUT; m += 64) {
                        const float4 u0 = ldsx[rp0][m], u1 = ldsx[rp0 + 1][m];
                        v.x += u0.x + u1.x; v.y += u0.y + u1.y;
                        v.z += u0.z + u1.z; v.w += u0.w + u1.w;
                    }
#pragma unroll
                    for (int o = 32; o >= 1; o >>= 1) {
                        v.x += __shfl_xor(v.x, o); v.y += __shfl_xor(v.y, o);
                        v.z += __shfl_xor(v.z, o); v.w += __shfl_xor(v.w, o);
                    }
                    const float cf = cfb[a];
                    a0l.x = fmaf(cf, v.x, a0l.x); a0l.y = fmaf(cf, v.y, a0l.y);
                    a0h.x = fmaf(cf, v.z, a0h.x); a0h.y = fmaf(cf, v.w, a0h.y);
                    a1l.x = fmaf(cf, v.x, a1l.x); a1l.y = fmaf(cf, v.y, a1l.y);
                    a1h.x = fmaf(cf, v.z, a1h.x); a1h.y = fmaf(cf, v.w, a1h.y);
                    a2l.x = fmaf(cf, v.x, a2l.x); a2l.y = fmaf(cf, v.y, a2l.y);
                    a2h.x = fmaf(cf, v.z, a2h.x); a2h.y = fmaf(cf, v.w, a2h.y);
                    continue;
                }
                const int rc = runcnt[idx];
                for (int rr = 0; rr < rc; ++rr) {
                    const uint2 R = runslab[a + rr];
                    const int e0  = __builtin_amdgcn_readfirstlane((int)R.x);
                    const int y   = __builtin_amdgcn_readfirstlane((int)R.y);
                    const int s0A = y & 511;
                    const int odd = (y >> 9) & 1;
                    const int len = y >> 11;
                    int qA = s0A - p0 - 2; qA += (qA >> 31) & NLON_OUT;
                    const char* baseA = lb + (size_t)(rp0 + odd) * ROWB + ((size_t)qA << 4);
                    const char* baseB = lb + (size_t)(rp0 + (odd ^ 1)) * ROWB
                                           + ((size_t)(qA + odd) << 4);
                    const float* cfp = cfb + e0;
                    int i = 0;
                    if (len >= 8) {
                        v2f A0l = *(const v2f*)(baseA +  0), A0h = *(const v2f*)(baseA +  8);
                        v2f A1l = *(const v2f*)(baseA + 16), A1h = *(const v2f*)(baseA + 24);
                        v2f A2l = *(const v2f*)(baseA + 32), A2h = *(const v2f*)(baseA + 40);
                        v2f B0l = *(const v2f*)(baseB +  0), B0h = *(const v2f*)(baseB +  8);
                        v2f B1l = *(const v2f*)(baseB + 16), B1h = *(const v2f*)(baseB + 24);
                        v2f B2l = *(const v2f*)(baseB + 32), B2h = *(const v2f*)(baseB + 40);
                        v2f A3l, A3h, B3l, B3h;
                        const char* ldA = baseA + 48;
                        const char* ldB = baseB + 48;
                        for (; i + 8 <= len; i += 8) {
                            float cs; v2f c;
                            A3l = *(const v2f*)(ldA); A3h = *(const v2f*)(ldA + 8); ldA += 16;
                            cs = cfp[i + 0]; c = (v2f){cs, cs};
                            PKF(a2l, A0l, c); PKF(a2h, A0h, c);
                            PKF(a1l, A1l, c); PKF(a1h, A1h, c);
                            PKF(a0l, A2l, c); PKF(a0h, A2h, c);
                            B3l = *(const v2f*)(ldB); B3h = *(const v2f*)(ldB + 8); ldB += 16;
                            cs = cfp[i + 1]; c = (v2f){cs, cs};
                            PKF(a2l, B0l, c); PKF(a2h, B0h, c);
                            PKF(a1l, B1l, c); PKF(a1h, B1h, c);
                            PKF(a0l, B2l, c); PKF(a0h, B2h, c);
                            A0l = *(const v2f*)(ldA); A0h = *(const v2f*)(ldA + 8); ldA += 16;
                            cs = cfp[i + 2]; c = (v2f){cs, cs};
                            PKF(a2l, A1l, c); PKF(a2h, A1h, c);
                            PKF(a1l, A2l, c); PKF(a1h, A2h, c);
                            PKF(a0l, A3l, c); PKF(a0h, A3h, c);
                            B0l = *(const v2f*)(ldB); B0h = *(const v2f*)(ldB + 8); ldB += 16;
                            cs = cfp[i + 3]; c = (v2f){cs, cs};
                            PKF(a2l, B1l, c); PKF(a2h, B1h, c);
                            PKF(a1l, B2l, c); PKF(a1h, B2h, c);
                            PKF(a0l, B3l, c); PKF(a0h, B3h, c);
                            A1l = *(const v2f*)(ldA); A1h = *(const v2f*)(ldA + 8); ldA += 16;
                            cs = cfp[i + 4]; c = (v2f){cs, cs};
                            PKF(a2l, A2l, c); PKF(a2h, A2h, c);
                            PKF(a1l, A3l, c); PKF(a1h, A3h, c);
                            PKF(a0l, A0l, c); PKF(a0h, A0h, c);
                            B1l = *(const v2f*)(ldB); B1h = *(const v2f*)(ldB + 8); ldB += 16;
                            cs = cfp[i + 5]; c = (v2f){cs, cs};
                            PKF(a2l, B2l, c); PKF(a2h, B2h, c);
                            PKF(a1l, B3l, c); PKF(a1h, B3h, c);
                            PKF(a0l, B0l, c); PKF(a0h, B0h, c);
                            A2l = *(const v2f*)(ldA); A2h = *(const v2f*)(ldA + 8); ldA += 16;
                            cs = cfp[i + 6]; c = (v2f){cs, cs};
                            PKF(a2l, A3l, c); PKF(a2h, A3h, c);
                            PKF(a1l, A0l, c); PKF(a1h, A0h, c);
                            PKF(a0l, A1l, c); PKF(a0h, A1h, c);
                            B2l = *(const v2f*)(ldB); B2h = *(const v2f*)(ldB + 8); ldB += 16;
                            cs = cfp[i + 7]; c = (v2f){cs, cs};
                            PKF(a2l, B3l, c); PKF(a2h, B3h, c);
                            PKF(a1l, B0l, c); PKF(a1h, B0h, c);
                            PKF(a0l, B1l, c); PKF(a0h, B1h, c);
                        }
                    }
                    for (; i < len; ++i) {       // tail / short runs
                        const int m = i >> 1;
                        const char* bp = (i & 1) ? (baseB + ((size_t)m << 4))
                                                 : (baseA + ((size_t)m << 4));
                        const float cs = cfp[i]; const v2f c = (v2f){cs, cs};
                        const v2f w0l = *(const v2f*)(bp +  0), w0h = *(const v2f*)(bp +  8);
                        const v2f w1l = *(const v2f*)(bp + 16), w1h = *(const v2f*)(bp + 24);
                        const v2f w2l = *(const v2f*)(bp + 32), w2h = *(const v2f*)(bp + 40);
                        PKF(a2l, w0l, c); PKF(a2h, w0h, c);
                        PKF(a1l, w1l, c); PKF(a1h, w1h, c);
                        PKF(a0l, w2l, c); PKF(a0h, w2h, c);
                    }
                }
            }
        }
    }

    // ---- combine pair-1 into pair-0, store ----
    __syncthreads();
    if (wpair == 1 && pairlane < 120) {
        accbuf[pid][0] = a0l; accbuf[pid][1] = a0h;
        accbuf[pid][2] = a1l; accbuf[pid][3] = a1h;
        accbuf[pid][4] = a2l; accbuf[pid][5] = a2h;
    }
    __syncthreads();
    if (wpair == 0 && pairlane < 120) {
        a0l += accbuf[pid][0]; a0h += accbuf[pid][1];
        a1l += accbuf[pid][2]; a1h += accbuf[pid][3];
        a2l += accbuf[pid][4]; a2h += accbuf[pid][5];
        const size_t cs_ = (size_t)NSEG * NLON_OUT;
        const size_t ob  = ((size_t)bc0 * NSEG + s) * NLON_OUT + p0;
        out[ob]              = a0l.x; out[ob + 1]              = a1l.x; out[ob + 2]              = a2l.x;
        out[ob + cs_]        = a0l.y; out[ob + cs_ + 1]        = a1l.y; out[ob + cs_ + 2]        = a2l.y;
        out[ob + 2 * cs_]    = a0h.x; out[ob + 2 * cs_ + 1]    = a1h.x; out[ob + 2 * cs_ + 2]    = a2h.x;
        out[ob + 3 * cs_]    = a0h.y; out[ob + 3 * cs_ + 1]    = a1h.y; out[ob + 3 * cs_ + 2]    = a2h.y;
    }
#undef LOADW
#undef WRITEW
}

// ---------------- fallback (tiny ws) ----------------

__global__ void segptr_kernel(const int* __restrict__ seg, int nnz, int* __restrict__ ptr) {
    int s = blockIdx.x * blockDim.x + threadIdx.x;
    if (s > NSEG) return;
    if (s == NSEG) { ptr[NSEG] = nnz; return; }
    int lo = 0, hi = nnz;
    while (lo < hi) { int m = (lo + hi) >> 1; if (seg[m] < s) lo = m + 1; else hi = m; }
    ptr[s] = lo;
}

__global__ __launch_bounds__(384) void disco_simple_kernel(
    const float* __restrict__ x, const float* __restrict__ qw,
    const int* __restrict__ lat, const int* __restrict__ lon,
    const float* __restrict__ val, const int* __restrict__ ptr,
    float* __restrict__ out)
{
    const int p = threadIdx.x;
    if (p >= NLON_OUT) return;
    const int kt = blockIdx.x, bc0 = blockIdx.y * 8;
    const int e0 = ptr[kt], e1 = ptr[kt + 1];
    float acc[8];
#pragma unroll
    for (int g = 0; g < 8; ++g) acc[g] = 0.0f;
    const int pw = 2 * p + 2;
    const float* xb = x + (size_t)bc0 * CHW;
    for (int e = e0; e < e1; ++e) {
        const int h = lat[e], w = lon[e];
        const float cf = val[e] * qw[h];
        int col = w - pw; if (col < 0) col += NLON_IN;
        const float* src = xb + h * NLON_IN + col;
#pragma unroll
        for (int g = 0; g < 8; ++g) acc[g] = fmaf(cf, src[(size_t)g * CHW], acc[g]);
    }
    const size_t ob = ((size_t)bc0 * NSEG + kt) * NLON_OUT + p;
#pragma unroll
    for (int g = 0; g < 8; ++g) out[ob + (size_t)g * NSEG * NLON_OUT] = acc[g];
}

// ---------------- launcher ----------------

extern "C" void kernel_launch(void* const* d_in, const int* in_sizes, int n_in,
                              void* d_out, int out_size, void* d_ws, size_t ws_size,
                              hipStream_t stream)
{
    const float* x   = (const float*)d_in[0];   // [2,64,360,720] f32
    const float* qw  = (const float*)d_in[1];   // [360,1] f32
    const int*   seg = (const int*)  d_in[2];   // [nnz] i32 sorted asc
    const int*   lat = (const int*)  d_in[3];
    const int*   lon = (const int*)  d_in[4];
    const float* val = (const float*)d_in[5];
    const int    nnz = in_sizes[2];
    const int    nnzpad = (nnz + 3) & ~3;

    char* w = (char*)d_ws;
    size_t off = 0;
    int* ptrh   = (int*)(w + off); off += (size_t)NSEG * PH * 4;   // 21600
    int* hbase  = (int*)(w + off); off += NSEG * 4;
    int* hlast  = (int*)(w + off); off += NSEG * 4;
    int* flags  = (int*)(w + off); off += (size_t)NSEG * PH * 4;
    int* runcnt = (int*)(w + off); off += (size_t)NSEG * PH * 4;
    float* cfb  = (float*)(w + off); off += (size_t)nnzpad * 4;
    off = (off + 7) & ~(size_t)7;
    uint2* runslab = (uint2*)(w + off); off += (size_t)nnz * 8;

    if (ws_size < off) {                         // tiny ws: slow-but-correct path
        int* ptr = (int*)d_ws;
        segptr_kernel<<<(NSEG + 1 + 255) / 256, 256, 0, stream>>>(seg, nnz, ptr);
        dim3 grid(NSEG, BCTOT / 8);
        disco_simple_kernel<<<grid, 384, 0, stream>>>(x, qw, lat, lon, val, ptr,
                                                      (float*)d_out);
        return;
    }

    prep1_kernel<<<(NSEG * PH + 255) / 256, 256, 0, stream>>>(seg, lat, val, nnz,
                                                              ptrh, hbase, hlast, flags);
    cf_kernel<<<(nnz + 255) / 256, 256, 0, stream>>>(lat, val, qw, nnz, cfb);
    runs_kernel<<<(NSEG * PH + 3) / 4, 256, 0, stream>>>(lon, ptrh, flags,
                                                         runcnt, runslab);

    dim3 grid(NBCG, NLAT_OUT, KSIZE);
    disco_kernel<<<grid, NTHREADS, 0, stream>>>(x, cfb, runslab, runcnt,
                                                ptrh, hbase, hlast, flags,
                                                (float*)d_out);
}